// Round 3
// baseline (1787.454 us; speedup 1.0000x reference)
//
#include <hip/hip_runtime.h>
#include <math.h>

#define BSZ 2
#define CHN 64
#define NPT 400
#define LW  12
#define DM  128
#define NH  8
#define HDM 16
#define FFD 1024
#define NTOK (BSZ*LW*NPT)   // 9600

// ------------------------------------------------------------------
// Stage A: QKV projections + per-head l2norm.
// out layout: [b][l][h][n][d]  (contiguous 400x16 slice per (b,l,h))
// ------------------------------------------------------------------
#define TA 16
__global__ __launch_bounds__(128) void stage_a(
    const float* __restrict__ x, const float* __restrict__ xa1, const float* __restrict__ xa2,
    const float* __restrict__ WQ1, const float* __restrict__ bQ1,
    const float* __restrict__ WQ2, const float* __restrict__ bQ2,
    const float* __restrict__ WK1, const float* __restrict__ bK1,
    const float* __restrict__ WK2, const float* __restrict__ bK2,
    const float* __restrict__ WV,  const float* __restrict__ bV,
    float* __restrict__ q1n, float* __restrict__ q2n,
    float* __restrict__ k1n, float* __restrict__ k2n, float* __restrict__ vv)
{
  __shared__ float xv[TA][CHN], a1v[TA][CHN], a2v[TA][CHN];
  const int tid = threadIdx.x;
  const int t0 = blockIdx.x * TA;
  for (int i = tid; i < TA*CHN; i += 128) {
    int tt = i & (TA-1), c = i >> 4;
    int token = t0 + tt;
    int n = token % NPT; int bl = token / NPT; int l = bl % LW; int b = bl / LW;
    int gidx = ((b*CHN + c)*NPT + n)*LW + l;
    xv[tt][c] = x[gidx]; a1v[tt][c] = xa1[gidx]; a2v[tt][c] = xa2[gidx];
  }
  __syncthreads();
  const int d = tid;  // 0..127
  float aq1[TA], aq2[TA], ak1[TA], ak2[TA], av[TA];
  float b1 = bQ1[d], b2 = bQ2[d], b3 = bK1[d], b4 = bK2[d], b5 = bV[d];
  #pragma unroll
  for (int t = 0; t < TA; ++t) { aq1[t]=b1; aq2[t]=b2; ak1[t]=b3; ak2[t]=b4; av[t]=b5; }
  for (int c = 0; c < CHN; ++c) {
    float w1 = WQ1[c*DM + d], w2 = WQ2[c*DM + d], w3 = WK1[c*DM + d],
          w4 = WK2[c*DM + d], w5 = WV[c*DM + d];
    #pragma unroll
    for (int t = 0; t < TA; ++t) {
      float xc = xv[t][c], x1 = a1v[t][c], x2 = a2v[t][c];
      aq1[t] += x1*w1; aq2[t] += x2*w2; ak1[t] += xc*w3; ak2[t] += xc*w4; av[t] += xc*w5;
    }
  }
  const int h = d >> 4, dd = d & 15;
  #pragma unroll
  for (int t = 0; t < TA; ++t) {
    float s1 = aq1[t]*aq1[t], s2 = aq2[t]*aq2[t], s3 = ak1[t]*ak1[t], s4 = ak2[t]*ak2[t];
    #pragma unroll
    for (int m = 1; m < 16; m <<= 1) {
      s1 += __shfl_xor(s1, m); s2 += __shfl_xor(s2, m);
      s3 += __shfl_xor(s3, m); s4 += __shfl_xor(s4, m);
    }
    float i1 = 1.f/fmaxf(sqrtf(s1),1e-12f), i2 = 1.f/fmaxf(sqrtf(s2),1e-12f),
          i3 = 1.f/fmaxf(sqrtf(s3),1e-12f), i4 = 1.f/fmaxf(sqrtf(s4),1e-12f);
    int token = t0 + t;
    int n = token % NPT; int bl = token / NPT; int l = bl % LW; int b = bl / LW;
    int base = (((b*LW + l)*NH + h)*NPT + n)*HDM + dd;
    q1n[base] = aq1[t]*i1; q2n[base] = aq2[t]*i2;
    k1n[base] = ak1[t]*i3; k2n[base] = ak2[t]*i4; vv[base] = av[t];
  }
}

// ------------------------------------------------------------------
// Stage B: fused dual-cosine attention + exact top-k dual softmax + PV
// Grid: (b,h,l, split s of 100 rows) = 768 WGs x 256 threads
// v3: K1/K2 in LDS only (51.3KB -> 3 WGs/CU); V read from global
//     (L2-resident slice); PV split into two d-halves (buf 64->32);
//     dual radix descents merged into one bit loop with uniform
//     done-guards (skip finished descent's ballots).
// ------------------------------------------------------------------
__device__ __forceinline__ unsigned okey(float xf) {
  unsigned u = __float_as_uint(xf);
  return (u & 0x80000000u) ? ~u : (u | 0x80000000u);
}

__global__ __launch_bounds__(256, 3) void stage_b(
    const float* __restrict__ q1n, const float* __restrict__ q2n,
    const float* __restrict__ k1n, const float* __restrict__ k2n,
    const float* __restrict__ vv,
    const float* __restrict__ temperature, const float* __restrict__ alphas,
    float* __restrict__ attn_o, float* __restrict__ p2_o, float* __restrict__ oa)
{
  // d-chunk planes, stride 401 float4 per plane: stride-1 b128 reads, conflict-free
  __shared__ float4 k1s[4*401], k2s[4*401];
  int wg = blockIdx.x;
  const int s = wg & 3; wg >>= 2;
  const int l = wg % LW; wg /= LW;
  const int h = wg & 7; const int b = wg >> 3;
  const int tid = threadIdx.x, lane = tid & 63, wave = tid >> 6;

  const int slice = (b*LW + l)*NH + h;          // internal q/k/v layout [b][l][h]
  const int oslice = (b*NH + h)*LW + l;         // OUTPUT layout [b][h][l] (reshape bs*H, L, N, N)
  const float4* k1g = (const float4*)(k1n + slice*NPT*HDM);
  const float4* k2g = (const float4*)(k2n + slice*NPT*HDM);
  const float4* vg4 = (const float4*)(vv  + slice*NPT*HDM);
  for (int i = tid; i < NPT*4; i += 256) {
    int m = i >> 2, w4 = i & 3;
    k1s[w4*401 + m] = k1g[i];
    k2s[w4*401 + m] = k2g[i];
  }
  __syncthreads();

  const float temp = temperature[h];
  float a0 = alphas[0], a1 = alphas[1];
  float amx = fmaxf(a0, a1);
  float e0 = __expf(a0 - amx), e1 = __expf(a1 - amx);
  float al0 = e0/(e0+e1), al1 = e1/(e0+e1);

  const float* q1base = q1n + slice*NPT*HDM;
  const float* q2base = q2n + slice*NPT*HDM;
  float* attn_base = attn_o + (size_t)oslice*NPT*NPT;
  float* p2_base   = p2_o   + (size_t)oslice*NPT*NPT;
  const int tokbase = (b*LW + l)*NPT;

  for (int bi = wave; bi < 25; bi += 4) {
    const int nb = s*100 + bi*4;    // rows nb..nb+3
    float sc[4][7];
    #pragma unroll
    for (int r = 0; r < 4; ++r)
      #pragma unroll
      for (int j = 0; j < 7; ++j) sc[r][j] = 0.f;

    // ---- scores: Q1.K1 + Q2.K2 over d (16+16), 4 rows x 7 m's/lane ----
    // Q addresses are wave-uniform -> compiler scalarizes to SGPRs.
    #pragma unroll
    for (int ch = 0; ch < 4; ++ch) {
      float4 q1c[4], q2c[4];
      #pragma unroll
      for (int r = 0; r < 4; ++r) {
        q1c[r] = *(const float4*)(q1base + (nb+r)*HDM + ch*4);
        q2c[r] = *(const float4*)(q2base + (nb+r)*HDM + ch*4);
      }
      #pragma unroll
      for (int j = 0; j < 7; ++j) {
        int m = lane + 64*j;
        if (j < 6 || lane < 16) {
          float4 kc1 = k1s[ch*401 + m];
          float4 kc2 = k2s[ch*401 + m];
          #pragma unroll
          for (int r = 0; r < 4; ++r) {
            sc[r][j] += q1c[r].x*kc1.x + q1c[r].y*kc1.y + q1c[r].z*kc1.z + q1c[r].w*kc1.w
                      + q2c[r].x*kc2.x + q2c[r].y*kc2.y + q2c[r].z*kc2.z + q2c[r].w*kc2.w;
          }
        }
      }
    }
    // ---- temperature + attn output ----
    #pragma unroll
    for (int r = 0; r < 4; ++r) {
      #pragma unroll
      for (int j = 0; j < 7; ++j) {
        sc[r][j] *= temp;
        int m = lane + 64*j;
        if (j < 6 || lane < 16) attn_base[(nb + r)*NPT + m] = sc[r][j];
      }
    }
    // ---- per-row: exact top-k select + dual softmax; overwrite sc with w ----
    #pragma unroll
    for (int r = 0; r < 4; ++r) {
      unsigned key[7];
      #pragma unroll
      for (int j = 0; j < 7; ++j) {
        bool valid = (j < 6) || (lane < 16);
        key[j] = valid ? okey(sc[r][j]) : 0u;
      }
      float am = -3.4e38f;
      #pragma unroll
      for (int j = 0; j < 7; ++j) if ((j < 6) || (lane < 16)) am = fmaxf(am, sc[r][j]);
      #pragma unroll
      for (int m2 = 1; m2 < 64; m2 <<= 1) am = fmaxf(am, __shfl_xor(am, m2));

      // merged dual radix descent: v1 (k=200) and v2 (k=100) in one bit loop.
      // The two serial chains overlap; d1/d2 are wave-uniform so the guards
      // are cheap s_cbranch and the finished descent stops issuing ballots.
      unsigned v1 = 0u, v2 = 0u;
      bool d1 = false, d2 = false;
      #pragma clang loop unroll(disable)
      for (int bit = 31; bit >= 0; --bit) {
        if (!d1) {
          unsigned T1 = v1 | (1u << bit);
          int c1 = 0;
          #pragma unroll
          for (int j = 0; j < 7; ++j) c1 += __popcll(__ballot(key[j] >= T1));
          if (c1 >= 200) { v1 = T1; if (c1 == 200) d1 = true; }
        }
        if (!d2) {
          unsigned T2 = v2 | (1u << bit);
          int c2 = 0;
          #pragma unroll
          for (int j = 0; j < 7; ++j) c2 += __popcll(__ballot(key[j] >= T2));
          if (c2 >= 100) { v2 = T2; if (c2 == 100) d2 = true; }
        }
        if (d1 && d2) break;
      }

      float e[7]; float s1 = 0.f, s2 = 0.f;
      #pragma unroll
      for (int j = 0; j < 7; ++j) {
        e[j] = ((j < 6) || (lane < 16)) ? __expf(sc[r][j] - am) : 0.f;
        s1 += (key[j] >= v1) ? e[j] : 0.f;
        s2 += (key[j] >= v2) ? e[j] : 0.f;
      }
      #pragma unroll
      for (int m2 = 1; m2 < 64; m2 <<= 1) { s1 += __shfl_xor(s1, m2); s2 += __shfl_xor(s2, m2); }
      float rz1 = 1.f / s1, rz2 = 1.f / s2;
      float c1 = al0 * rz1, c2 = al1 * rz2;
      #pragma unroll
      for (int j = 0; j < 7; ++j) {
        int m = lane + 64*j;
        float p2v = (key[j] >= v2) ? e[j]*rz2 : 0.f;
        if ((j < 6) || (lane < 16)) p2_base[(nb + r)*NPT + m] = p2v;
        sc[r][j] = e[j] * (((key[j] >= v1) ? c1 : 0.f) + ((key[j] >= v2) ? c2 : 0.f));
      }
    }
    // ---- PV in two d-halves: out[r][half*8+dd] = sum_m w[r][m]*v[m][...] ----
    // V comes straight from global (25.6KB slice -> L2-resident); halves read
    // disjoint float4 planes so total V traffic equals the old LDS version.
    #pragma unroll
    for (int half = 0; half < 2; ++half) {
      float buf[32];
      #pragma unroll
      for (int i = 0; i < 32; ++i) buf[i] = 0.f;
      #pragma unroll
      for (int j = 0; j < 7; ++j) {
        int m = lane + 64*j;
        if (j < 6 || lane < 16) {
          float4 w0 = vg4[m*4 + half*2 + 0];
          float4 w1 = vg4[m*4 + half*2 + 1];
          #pragma unroll
          for (int r = 0; r < 4; ++r) {
            float wr = sc[r][j];
            buf[r*8+0] += wr*w0.x; buf[r*8+1] += wr*w0.y;
            buf[r*8+2] += wr*w0.z; buf[r*8+3] += wr*w0.w;
            buf[r*8+4] += wr*w1.x; buf[r*8+5] += wr*w1.y;
            buf[r*8+6] += wr*w1.z; buf[r*8+7] += wr*w1.w;
          }
        }
      }
      // reduce-scatter 32 elems over lanes (bits 0..4), then fold lane^32.
      #pragma unroll
      for (int st = 0; st < 5; ++st) {
        int bsel = (lane >> st) & 1;
        #pragma unroll
        for (int u = 0; u < (32 >> (st+1)); ++u) {
          float lo = buf[2*u], hi = buf[2*u+1];
          float keep = bsel ? hi : lo;
          float send = bsel ? lo : hi;
          float recv = __shfl_xor(send, 1 << st);
          buf[u] = keep + recv;
        }
      }
      float res = buf[0] + __shfl_xor(buf[0], 32);
      if (lane < 32) {
        int rr = lane >> 3, dlo = lane & 7;
        oa[(tokbase + nb + rr)*DM + h*HDM + half*8 + dlo] = res;
      }
    }
  }
}

// ------------------------------------------------------------------
// Stage C: Wo + residual + LN1 + FF + LN2 + transpose-out
// Grid: 300 WGs x 256 threads, 32 tokens/WG
// ------------------------------------------------------------------
#define TC 32
__global__ __launch_bounds__(256, 2) void stage_c(
    const float* __restrict__ oa, const float* __restrict__ x,
    const float* __restrict__ Wo, const float* __restrict__ bo,
    const float* __restrict__ Wf1, const float* __restrict__ bf1,
    const float* __restrict__ Wf2, const float* __restrict__ bf2,
    const float* __restrict__ g1, const float* __restrict__ be1,
    const float* __restrict__ g2, const float* __restrict__ be2,
    float* __restrict__ outp)
{
  __shared__ float4 oa_lds[TC*32];   // 16 KB
  __shared__ float4 y1_lds[TC*16];   // 8 KB
  __shared__ float4 act_lds[TC*64];  // 32 KB
  const int tid = threadIdx.x;
  const int t0 = blockIdx.x * TC;
  const float4* oag = (const float4*)(oa + t0*DM);
  for (int i = tid; i < TC*32; i += 256) oa_lds[i] = oag[i];
  __syncthreads();

  const int c = tid & 63, g = tid >> 6;   // tokens tt = g + 4k, k=0..7
  float bo_c = bo[c], g1c = g1[c], be1c = be1[c], g2c = g2[c], be2c = be2[c], bf2c = bf2[c];

  // P1: o1 = oa @ Wo + bo
  float o1[8];
  #pragma unroll
  for (int k = 0; k < 8; ++k) o1[k] = bo_c;
  for (int d4 = 0; d4 < 32; ++d4) {
    float w0 = Wo[(4*d4+0)*CHN + c];
    float w1 = Wo[(4*d4+1)*CHN + c];
    float w2 = Wo[(4*d4+2)*CHN + c];
    float w3 = Wo[(4*d4+3)*CHN + c];
    #pragma unroll
    for (int k = 0; k < 8; ++k) {
      float4 u = oa_lds[(g + 4*k)*32 + d4];
      o1[k] += u.x*w0 + u.y*w1 + u.z*w2 + u.w*w3;
    }
  }
  // residual + LN1
  float y1r[8];
  #pragma unroll
  for (int k = 0; k < 8; ++k) {
    int token = t0 + g + 4*k;
    int n = token % NPT; int bl = token / NPT; int l = bl % LW; int b = bl / LW;
    float val = o1[k] + x[((b*CHN + c)*NPT + n)*LW + l];
    float sm = val, sq = val*val;
    #pragma unroll
    for (int m2 = 1; m2 < 64; m2 <<= 1) { sm += __shfl_xor(sm, m2); sq += __shfl_xor(sq, m2); }
    float mean = sm * (1.f/64.f);
    float var = sq * (1.f/64.f) - mean*mean;
    float y = (val - mean) * rsqrtf(var + 1e-5f) * g1c + be1c;
    y1r[k] = y;
    ((float*)y1_lds)[(g + 4*k)*CHN + c] = y;
  }
  __syncthreads();

  float o2a[8];
  #pragma unroll
  for (int k = 0; k < 8; ++k) o2a[k] = 0.f;

  for (int fb = 0; fb < 4; ++fb) {
    // 2a: act = relu(y1 @ Wf1 + bf1) for 256 f's
    {
      const int ft = tid & 63, ga = tid >> 6;
      const int f = fb*256 + ft*4;
      float4 facc[8];
      float4 bb = *(const float4*)(bf1 + f);
      #pragma unroll
      for (int k = 0; k < 8; ++k) facc[k] = bb;
      for (int c4 = 0; c4 < 16; ++c4) {
        float4 w0 = *(const float4*)(Wf1 + (4*c4+0)*FFD + f);
        float4 w1 = *(const float4*)(Wf1 + (4*c4+1)*FFD + f);
        float4 w2 = *(const float4*)(Wf1 + (4*c4+2)*FFD + f);
        float4 w3 = *(const float4*)(Wf1 + (4*c4+3)*FFD + f);
        #pragma unroll
        for (int k = 0; k < 8; ++k) {
          float4 y4 = y1_lds[(ga + 4*k)*16 + c4];
          facc[k].x += y4.x*w0.x + y4.y*w1.x + y4.z*w2.x + y4.w*w3.x;
          facc[k].y += y4.x*w0.y + y4.y*w1.y + y4.z*w2.y + y4.w*w3.y;
          facc[k].z += y4.x*w0.z + y4.y*w1.z + y4.z*w2.z + y4.w*w3.z;
          facc[k].w += y4.x*w0.w + y4.y*w1.w + y4.z*w2.w + y4.w*w3.w;
        }
      }
      #pragma unroll
      for (int k = 0; k < 8; ++k) {
        float4 rv;
        rv.x = fmaxf(facc[k].x, 0.f); rv.y = fmaxf(facc[k].y, 0.f);
        rv.z = fmaxf(facc[k].z, 0.f); rv.w = fmaxf(facc[k].w, 0.f);
        act_lds[(ga + 4*k)*64 + ft] = rv;
      }
    }
    __syncthreads();
    // 2b: o2 += act @ Wf2
    for (int f4 = 0; f4 < 64; ++f4) {
      int f = fb*256 + f4*4;
      float w0 = Wf2[(f+0)*CHN + c];
      float w1 = Wf2[(f+1)*CHN + c];
      float w2 = Wf2[(f+2)*CHN + c];
      float w3 = Wf2[(f+3)*CHN + c];
      #pragma unroll
      for (int k = 0; k < 8; ++k) {
        float4 a4 = act_lds[(g + 4*k)*64 + f4];
        o2a[k] += a4.x*w0 + a4.y*w1 + a4.z*w2 + a4.w*w3;
      }
    }
    __syncthreads();
  }
  // P3: + bf2, residual y1, LN2, transposed store
  #pragma unroll
  for (int k = 0; k < 8; ++k) {
    int token = t0 + g + 4*k;
    int n = token % NPT; int bl = token / NPT; int l = bl % LW; int b = bl / LW;
    float val = y1r[k] + o2a[k] + bf2c;
    float sm = val, sq = val*val;
    #pragma unroll
    for (int m2 = 1; m2 < 64; m2 <<= 1) { sm += __shfl_xor(sm, m2); sq += __shfl_xor(sq, m2); }
    float mean = sm * (1.f/64.f);
    float var = sq * (1.f/64.f) - mean*mean;
    float y = (val - mean) * rsqrtf(var + 1e-5f) * g2c + be2c;
    outp[((b*CHN + c)*NPT + n)*LW + l] = y;
  }
}

// ------------------------------------------------------------------
extern "C" void kernel_launch(void* const* d_in, const int* in_sizes, int n_in,
                              void* d_out, int out_size, void* d_ws, size_t ws_size,
                              hipStream_t stream) {
  const float* x    = (const float*)d_in[0];
  const float* xa1  = (const float*)d_in[1];
  const float* xa2  = (const float*)d_in[2];
  const float* WQ1  = (const float*)d_in[3];
  const float* bQ1  = (const float*)d_in[4];
  const float* WQ2  = (const float*)d_in[5];
  const float* bQ2  = (const float*)d_in[6];
  const float* WK1  = (const float*)d_in[7];
  const float* bK1  = (const float*)d_in[8];
  const float* WK2  = (const float*)d_in[9];
  const float* bK2  = (const float*)d_in[10];
  const float* WV   = (const float*)d_in[11];
  const float* bV   = (const float*)d_in[12];
  const float* Wo   = (const float*)d_in[13];
  const float* bo   = (const float*)d_in[14];
  const float* Wf1  = (const float*)d_in[15];
  const float* bf1  = (const float*)d_in[16];
  const float* Wf2  = (const float*)d_in[17];
  const float* bf2  = (const float*)d_in[18];
  const float* g1   = (const float*)d_in[19];
  const float* be1  = (const float*)d_in[20];
  const float* g2   = (const float*)d_in[21];
  const float* be2  = (const float*)d_in[22];
  const float* temp = (const float*)d_in[23];
  const float* alph = (const float*)d_in[24];

  float* outp   = (float*)d_out;
  float* attn_o = outp + (size_t)BSZ*CHN*NPT*LW;          // 614400
  float* p2_o   = attn_o + (size_t)BSZ*NH*LW*NPT*NPT;     // +30720000

  const size_t SLICE = (size_t)BSZ*LW*NH*NPT*HDM;         // 2457600
  float* w   = (float*)d_ws;
  float* q1n = w;             w += SLICE;
  float* q2n = w;             w += SLICE;
  float* k1n = w;             w += SLICE;
  float* k2n = w;             w += SLICE;
  float* vv  = w;             w += SLICE;
  float* oa  = w;             w += (size_t)NTOK*DM;

  stage_a<<<NTOK/TA, 128, 0, stream>>>(x, xa1, xa2, WQ1, bQ1, WQ2, bQ2,
                                       WK1, bK1, WK2, bK2, WV, bV,
                                       q1n, q2n, k1n, k2n, vv);
  stage_b<<<BSZ*NH*LW*4, 256, 0, stream>>>(q1n, q2n, k1n, k2n, vv,
                                           temp, alph, attn_o, p2_o, oa);
  stage_c<<<NTOK/TC, 256, 0, stream>>>(oa, x, Wo, bo, Wf1, bf1, Wf2, bf2,
                                       g1, be1, g2, be2, outp);
}

// Round 4
// 1754.916 us; speedup vs baseline: 1.0185x; 1.0185x over previous
//
#include <hip/hip_runtime.h>
#include <math.h>

#define BSZ 2
#define CHN 64
#define NPT 400
#define LW  12
#define DM  128
#define NH  8
#define HDM 16
#define FFD 1024
#define NTOK (BSZ*LW*NPT)   // 9600

// ------------------------------------------------------------------
// Stage A: QKV projections + per-head l2norm.
// out layout: [b][l][h][n][d]  (contiguous 400x16 slice per (b,l,h))
// ------------------------------------------------------------------
#define TA 16
__global__ __launch_bounds__(128) void stage_a(
    const float* __restrict__ x, const float* __restrict__ xa1, const float* __restrict__ xa2,
    const float* __restrict__ WQ1, const float* __restrict__ bQ1,
    const float* __restrict__ WQ2, const float* __restrict__ bQ2,
    const float* __restrict__ WK1, const float* __restrict__ bK1,
    const float* __restrict__ WK2, const float* __restrict__ bK2,
    const float* __restrict__ WV,  const float* __restrict__ bV,
    float* __restrict__ q1n, float* __restrict__ q2n,
    float* __restrict__ k1n, float* __restrict__ k2n, float* __restrict__ vv)
{
  __shared__ float xv[TA][CHN], a1v[TA][CHN], a2v[TA][CHN];
  const int tid = threadIdx.x;
  const int t0 = blockIdx.x * TA;
  for (int i = tid; i < TA*CHN; i += 128) {
    int tt = i & (TA-1), c = i >> 4;
    int token = t0 + tt;
    int n = token % NPT; int bl = token / NPT; int l = bl % LW; int b = bl / LW;
    int gidx = ((b*CHN + c)*NPT + n)*LW + l;
    xv[tt][c] = x[gidx]; a1v[tt][c] = xa1[gidx]; a2v[tt][c] = xa2[gidx];
  }
  __syncthreads();
  const int d = tid;  // 0..127
  float aq1[TA], aq2[TA], ak1[TA], ak2[TA], av[TA];
  float b1 = bQ1[d], b2 = bQ2[d], b3 = bK1[d], b4 = bK2[d], b5 = bV[d];
  #pragma unroll
  for (int t = 0; t < TA; ++t) { aq1[t]=b1; aq2[t]=b2; ak1[t]=b3; ak2[t]=b4; av[t]=b5; }
  for (int c = 0; c < CHN; ++c) {
    float w1 = WQ1[c*DM + d], w2 = WQ2[c*DM + d], w3 = WK1[c*DM + d],
          w4 = WK2[c*DM + d], w5 = WV[c*DM + d];
    #pragma unroll
    for (int t = 0; t < TA; ++t) {
      float xc = xv[t][c], x1 = a1v[t][c], x2 = a2v[t][c];
      aq1[t] += x1*w1; aq2[t] += x2*w2; ak1[t] += xc*w3; ak2[t] += xc*w4; av[t] += xc*w5;
    }
  }
  const int h = d >> 4, dd = d & 15;
  #pragma unroll
  for (int t = 0; t < TA; ++t) {
    float s1 = aq1[t]*aq1[t], s2 = aq2[t]*aq2[t], s3 = ak1[t]*ak1[t], s4 = ak2[t]*ak2[t];
    #pragma unroll
    for (int m = 1; m < 16; m <<= 1) {
      s1 += __shfl_xor(s1, m); s2 += __shfl_xor(s2, m);
      s3 += __shfl_xor(s3, m); s4 += __shfl_xor(s4, m);
    }
    float i1 = 1.f/fmaxf(sqrtf(s1),1e-12f), i2 = 1.f/fmaxf(sqrtf(s2),1e-12f),
          i3 = 1.f/fmaxf(sqrtf(s3),1e-12f), i4 = 1.f/fmaxf(sqrtf(s4),1e-12f);
    int token = t0 + t;
    int n = token % NPT; int bl = token / NPT; int l = bl % LW; int b = bl / LW;
    int base = (((b*LW + l)*NH + h)*NPT + n)*HDM + dd;
    q1n[base] = aq1[t]*i1; q2n[base] = aq2[t]*i2;
    k1n[base] = ak1[t]*i3; k2n[base] = ak2[t]*i4; vv[base] = av[t];
  }
}

// ------------------------------------------------------------------
// Stage B: fused dual-cosine attention + exact top-k dual softmax + PV
// Grid: (b,h,l, split s of 100 rows) = 768 WGs x 256 threads
// v4: counters showed 4.4 GB/dispatch TCC traffic (14x mandatory) at
//     3.2 TB/s == the entire duration; VALUBusy only 7%. Root cause:
//     attn/p2 streaming stores flush L2/L1, so per-wave V slice
//     re-reads (~1 GB aggregate) all miss. Fix: NON-TEMPORAL stores
//     for attn/p2 (write-once, never re-read) so V/K stay cache-
//     resident. Everything else unchanged from v3.
// ------------------------------------------------------------------
__device__ __forceinline__ unsigned okey(float xf) {
  unsigned u = __float_as_uint(xf);
  return (u & 0x80000000u) ? ~u : (u | 0x80000000u);
}

__global__ __launch_bounds__(256, 3) void stage_b(
    const float* __restrict__ q1n, const float* __restrict__ q2n,
    const float* __restrict__ k1n, const float* __restrict__ k2n,
    const float* __restrict__ vv,
    const float* __restrict__ temperature, const float* __restrict__ alphas,
    float* __restrict__ attn_o, float* __restrict__ p2_o, float* __restrict__ oa)
{
  // d-chunk planes, stride 401 float4 per plane: stride-1 b128 reads, conflict-free
  __shared__ float4 k1s[4*401], k2s[4*401];
  int wg = blockIdx.x;
  const int s = wg & 3; wg >>= 2;
  const int l = wg % LW; wg /= LW;
  const int h = wg & 7; const int b = wg >> 3;
  const int tid = threadIdx.x, lane = tid & 63, wave = tid >> 6;

  const int slice = (b*LW + l)*NH + h;          // internal q/k/v layout [b][l][h]
  const int oslice = (b*NH + h)*LW + l;         // OUTPUT layout [b][h][l] (reshape bs*H, L, N, N)
  const float4* k1g = (const float4*)(k1n + slice*NPT*HDM);
  const float4* k2g = (const float4*)(k2n + slice*NPT*HDM);
  const float4* vg4 = (const float4*)(vv  + slice*NPT*HDM);
  for (int i = tid; i < NPT*4; i += 256) {
    int m = i >> 2, w4 = i & 3;
    k1s[w4*401 + m] = k1g[i];
    k2s[w4*401 + m] = k2g[i];
  }
  __syncthreads();

  const float temp = temperature[h];
  float a0 = alphas[0], a1 = alphas[1];
  float amx = fmaxf(a0, a1);
  float e0 = __expf(a0 - amx), e1 = __expf(a1 - amx);
  float al0 = e0/(e0+e1), al1 = e1/(e0+e1);

  const float* q1base = q1n + slice*NPT*HDM;
  const float* q2base = q2n + slice*NPT*HDM;
  float* attn_base = attn_o + (size_t)oslice*NPT*NPT;
  float* p2_base   = p2_o   + (size_t)oslice*NPT*NPT;
  const int tokbase = (b*LW + l)*NPT;

  for (int bi = wave; bi < 25; bi += 4) {
    const int nb = s*100 + bi*4;    // rows nb..nb+3
    float sc[4][7];
    #pragma unroll
    for (int r = 0; r < 4; ++r)
      #pragma unroll
      for (int j = 0; j < 7; ++j) sc[r][j] = 0.f;

    // ---- scores: Q1.K1 + Q2.K2 over d (16+16), 4 rows x 7 m's/lane ----
    // Q addresses are wave-uniform -> compiler scalarizes to SGPRs.
    #pragma unroll
    for (int ch = 0; ch < 4; ++ch) {
      float4 q1c[4], q2c[4];
      #pragma unroll
      for (int r = 0; r < 4; ++r) {
        q1c[r] = *(const float4*)(q1base + (nb+r)*HDM + ch*4);
        q2c[r] = *(const float4*)(q2base + (nb+r)*HDM + ch*4);
      }
      #pragma unroll
      for (int j = 0; j < 7; ++j) {
        int m = lane + 64*j;
        if (j < 6 || lane < 16) {
          float4 kc1 = k1s[ch*401 + m];
          float4 kc2 = k2s[ch*401 + m];
          #pragma unroll
          for (int r = 0; r < 4; ++r) {
            sc[r][j] += q1c[r].x*kc1.x + q1c[r].y*kc1.y + q1c[r].z*kc1.z + q1c[r].w*kc1.w
                      + q2c[r].x*kc2.x + q2c[r].y*kc2.y + q2c[r].z*kc2.z + q2c[r].w*kc2.w;
          }
        }
      }
    }
    // ---- temperature + attn output (non-temporal: write-once stream) ----
    #pragma unroll
    for (int r = 0; r < 4; ++r) {
      #pragma unroll
      for (int j = 0; j < 7; ++j) {
        sc[r][j] *= temp;
        int m = lane + 64*j;
        if (j < 6 || lane < 16)
          __builtin_nontemporal_store(sc[r][j], &attn_base[(nb + r)*NPT + m]);
      }
    }
    // ---- per-row: exact top-k select + dual softmax; overwrite sc with w ----
    #pragma unroll
    for (int r = 0; r < 4; ++r) {
      unsigned key[7];
      #pragma unroll
      for (int j = 0; j < 7; ++j) {
        bool valid = (j < 6) || (lane < 16);
        key[j] = valid ? okey(sc[r][j]) : 0u;
      }
      float am = -3.4e38f;
      #pragma unroll
      for (int j = 0; j < 7; ++j) if ((j < 6) || (lane < 16)) am = fmaxf(am, sc[r][j]);
      #pragma unroll
      for (int m2 = 1; m2 < 64; m2 <<= 1) am = fmaxf(am, __shfl_xor(am, m2));

      // merged dual radix descent: v1 (k=200) and v2 (k=100) in one bit loop.
      // d1/d2 are wave-uniform -> guards are cheap s_cbranch; finished
      // descent stops issuing ballots.
      unsigned v1 = 0u, v2 = 0u;
      bool d1 = false, d2 = false;
      #pragma clang loop unroll(disable)
      for (int bit = 31; bit >= 0; --bit) {
        if (!d1) {
          unsigned T1 = v1 | (1u << bit);
          int c1 = 0;
          #pragma unroll
          for (int j = 0; j < 7; ++j) c1 += __popcll(__ballot(key[j] >= T1));
          if (c1 >= 200) { v1 = T1; if (c1 == 200) d1 = true; }
        }
        if (!d2) {
          unsigned T2 = v2 | (1u << bit);
          int c2 = 0;
          #pragma unroll
          for (int j = 0; j < 7; ++j) c2 += __popcll(__ballot(key[j] >= T2));
          if (c2 >= 100) { v2 = T2; if (c2 == 100) d2 = true; }
        }
        if (d1 && d2) break;
      }

      float e[7]; float s1 = 0.f, s2 = 0.f;
      #pragma unroll
      for (int j = 0; j < 7; ++j) {
        e[j] = ((j < 6) || (lane < 16)) ? __expf(sc[r][j] - am) : 0.f;
        s1 += (key[j] >= v1) ? e[j] : 0.f;
        s2 += (key[j] >= v2) ? e[j] : 0.f;
      }
      #pragma unroll
      for (int m2 = 1; m2 < 64; m2 <<= 1) { s1 += __shfl_xor(s1, m2); s2 += __shfl_xor(s2, m2); }
      float rz1 = 1.f / s1, rz2 = 1.f / s2;
      float c1 = al0 * rz1, c2 = al1 * rz2;
      #pragma unroll
      for (int j = 0; j < 7; ++j) {
        int m = lane + 64*j;
        float p2v = (key[j] >= v2) ? e[j]*rz2 : 0.f;
        if ((j < 6) || (lane < 16))
          __builtin_nontemporal_store(p2v, &p2_base[(nb + r)*NPT + m]);
        sc[r][j] = e[j] * (((key[j] >= v1) ? c1 : 0.f) + ((key[j] >= v2) ? c2 : 0.f));
      }
    }
    // ---- PV in two d-halves: out[r][half*8+dd] = sum_m w[r][m]*v[m][...] ----
    // V from global; with nt stores above, the 25.6KB slice stays L1/L2
    // resident across re-reads.
    #pragma unroll
    for (int half = 0; half < 2; ++half) {
      float buf[32];
      #pragma unroll
      for (int i = 0; i < 32; ++i) buf[i] = 0.f;
      #pragma unroll
      for (int j = 0; j < 7; ++j) {
        int m = lane + 64*j;
        if (j < 6 || lane < 16) {
          float4 w0 = vg4[m*4 + half*2 + 0];
          float4 w1 = vg4[m*4 + half*2 + 1];
          #pragma unroll
          for (int r = 0; r < 4; ++r) {
            float wr = sc[r][j];
            buf[r*8+0] += wr*w0.x; buf[r*8+1] += wr*w0.y;
            buf[r*8+2] += wr*w0.z; buf[r*8+3] += wr*w0.w;
            buf[r*8+4] += wr*w1.x; buf[r*8+5] += wr*w1.y;
            buf[r*8+6] += wr*w1.z; buf[r*8+7] += wr*w1.w;
          }
        }
      }
      // reduce-scatter 32 elems over lanes (bits 0..4), then fold lane^32.
      #pragma unroll
      for (int st = 0; st < 5; ++st) {
        int bsel = (lane >> st) & 1;
        #pragma unroll
        for (int u = 0; u < (32 >> (st+1)); ++u) {
          float lo = buf[2*u], hi = buf[2*u+1];
          float keep = bsel ? hi : lo;
          float send = bsel ? lo : hi;
          float recv = __shfl_xor(send, 1 << st);
          buf[u] = keep + recv;
        }
      }
      float res = buf[0] + __shfl_xor(buf[0], 32);
      if (lane < 32) {
        int rr = lane >> 3, dlo = lane & 7;
        oa[(tokbase + nb + rr)*DM + h*HDM + half*8 + dlo] = res;
      }
    }
  }
}

// ------------------------------------------------------------------
// Stage C: Wo + residual + LN1 + FF + LN2 + transpose-out
// Grid: 300 WGs x 256 threads, 32 tokens/WG
// ------------------------------------------------------------------
#define TC 32
__global__ __launch_bounds__(256, 2) void stage_c(
    const float* __restrict__ oa, const float* __restrict__ x,
    const float* __restrict__ Wo, const float* __restrict__ bo,
    const float* __restrict__ Wf1, const float* __restrict__ bf1,
    const float* __restrict__ Wf2, const float* __restrict__ bf2,
    const float* __restrict__ g1, const float* __restrict__ be1,
    const float* __restrict__ g2, const float* __restrict__ be2,
    float* __restrict__ outp)
{
  __shared__ float4 oa_lds[TC*32];   // 16 KB
  __shared__ float4 y1_lds[TC*16];   // 8 KB
  __shared__ float4 act_lds[TC*64];  // 32 KB
  const int tid = threadIdx.x;
  const int t0 = blockIdx.x * TC;
  const float4* oag = (const float4*)(oa + t0*DM);
  for (int i = tid; i < TC*32; i += 256) oa_lds[i] = oag[i];
  __syncthreads();

  const int c = tid & 63, g = tid >> 6;   // tokens tt = g + 4k, k=0..7
  float bo_c = bo[c], g1c = g1[c], be1c = be1[c], g2c = g2[c], be2c = be2[c], bf2c = bf2[c];

  // P1: o1 = oa @ Wo + bo
  float o1[8];
  #pragma unroll
  for (int k = 0; k < 8; ++k) o1[k] = bo_c;
  for (int d4 = 0; d4 < 32; ++d4) {
    float w0 = Wo[(4*d4+0)*CHN + c];
    float w1 = Wo[(4*d4+1)*CHN + c];
    float w2 = Wo[(4*d4+2)*CHN + c];
    float w3 = Wo[(4*d4+3)*CHN + c];
    #pragma unroll
    for (int k = 0; k < 8; ++k) {
      float4 u = oa_lds[(g + 4*k)*32 + d4];
      o1[k] += u.x*w0 + u.y*w1 + u.z*w2 + u.w*w3;
    }
  }
  // residual + LN1
  float y1r[8];
  #pragma unroll
  for (int k = 0; k < 8; ++k) {
    int token = t0 + g + 4*k;
    int n = token % NPT; int bl = token / NPT; int l = bl % LW; int b = bl / LW;
    float val = o1[k] + x[((b*CHN + c)*NPT + n)*LW + l];
    float sm = val, sq = val*val;
    #pragma unroll
    for (int m2 = 1; m2 < 64; m2 <<= 1) { sm += __shfl_xor(sm, m2); sq += __shfl_xor(sq, m2); }
    float mean = sm * (1.f/64.f);
    float var = sq * (1.f/64.f) - mean*mean;
    float y = (val - mean) * rsqrtf(var + 1e-5f) * g1c + be1c;
    y1r[k] = y;
    ((float*)y1_lds)[(g + 4*k)*CHN + c] = y;
  }
  __syncthreads();

  float o2a[8];
  #pragma unroll
  for (int k = 0; k < 8; ++k) o2a[k] = 0.f;

  for (int fb = 0; fb < 4; ++fb) {
    // 2a: act = relu(y1 @ Wf1 + bf1) for 256 f's
    {
      const int ft = tid & 63, ga = tid >> 6;
      const int f = fb*256 + ft*4;
      float4 facc[8];
      float4 bb = *(const float4*)(bf1 + f);
      #pragma unroll
      for (int k = 0; k < 8; ++k) facc[k] = bb;
      for (int c4 = 0; c4 < 16; ++c4) {
        float4 w0 = *(const float4*)(Wf1 + (4*c4+0)*FFD + f);
        float4 w1 = *(const float4*)(Wf1 + (4*c4+1)*FFD + f);
        float4 w2 = *(const float4*)(Wf1 + (4*c4+2)*FFD + f);
        float4 w3 = *(const float4*)(Wf1 + (4*c4+3)*FFD + f);
        #pragma unroll
        for (int k = 0; k < 8; ++k) {
          float4 y4 = y1_lds[(ga + 4*k)*16 + c4];
          facc[k].x += y4.x*w0.x + y4.y*w1.x + y4.z*w2.x + y4.w*w3.x;
          facc[k].y += y4.x*w0.y + y4.y*w1.y + y4.z*w2.y + y4.w*w3.y;
          facc[k].z += y4.x*w0.z + y4.y*w1.z + y4.z*w2.z + y4.w*w3.z;
          facc[k].w += y4.x*w0.w + y4.y*w1.w + y4.z*w2.w + y4.w*w3.w;
        }
      }
      #pragma unroll
      for (int k = 0; k < 8; ++k) {
        float4 rv;
        rv.x = fmaxf(facc[k].x, 0.f); rv.y = fmaxf(facc[k].y, 0.f);
        rv.z = fmaxf(facc[k].z, 0.f); rv.w = fmaxf(facc[k].w, 0.f);
        act_lds[(ga + 4*k)*64 + ft] = rv;
      }
    }
    __syncthreads();
    // 2b: o2 += act @ Wf2
    for (int f4 = 0; f4 < 64; ++f4) {
      int f = fb*256 + f4*4;
      float w0 = Wf2[(f+0)*CHN + c];
      float w1 = Wf2[(f+1)*CHN + c];
      float w2 = Wf2[(f+2)*CHN + c];
      float w3 = Wf2[(f+3)*CHN + c];
      #pragma unroll
      for (int k = 0; k < 8; ++k) {
        float4 a4 = act_lds[(g + 4*k)*64 + f4];
        o2a[k] += a4.x*w0 + a4.y*w1 + a4.z*w2 + a4.w*w3;
      }
    }
    __syncthreads();
  }
  // P3: + bf2, residual y1, LN2, transposed store
  #pragma unroll
  for (int k = 0; k < 8; ++k) {
    int token = t0 + g + 4*k;
    int n = token % NPT; int bl = token / NPT; int l = bl % LW; int b = bl / LW;
    float val = y1r[k] + o2a[k] + bf2c;
    float sm = val, sq = val*val;
    #pragma unroll
    for (int m2 = 1; m2 < 64; m2 <<= 1) { sm += __shfl_xor(sm, m2); sq += __shfl_xor(sq, m2); }
    float mean = sm * (1.f/64.f);
    float var = sq * (1.f/64.f) - mean*mean;
    float y = (val - mean) * rsqrtf(var + 1e-5f) * g2c + be2c;
    outp[((b*CHN + c)*NPT + n)*LW + l] = y;
  }
}

// ------------------------------------------------------------------
extern "C" void kernel_launch(void* const* d_in, const int* in_sizes, int n_in,
                              void* d_out, int out_size, void* d_ws, size_t ws_size,
                              hipStream_t stream) {
  const float* x    = (const float*)d_in[0];
  const float* xa1  = (const float*)d_in[1];
  const float* xa2  = (const float*)d_in[2];
  const float* WQ1  = (const float*)d_in[3];
  const float* bQ1  = (const float*)d_in[4];
  const float* WQ2  = (const float*)d_in[5];
  const float* bQ2  = (const float*)d_in[6];
  const float* WK1  = (const float*)d_in[7];
  const float* bK1  = (const float*)d_in[8];
  const float* WK2  = (const float*)d_in[9];
  const float* bK2  = (const float*)d_in[10];
  const float* WV   = (const float*)d_in[11];
  const float* bV   = (const float*)d_in[12];
  const float* Wo   = (const float*)d_in[13];
  const float* bo   = (const float*)d_in[14];
  const float* Wf1  = (const float*)d_in[15];
  const float* bf1  = (const float*)d_in[16];
  const float* Wf2  = (const float*)d_in[17];
  const float* bf2  = (const float*)d_in[18];
  const float* g1   = (const float*)d_in[19];
  const float* be1  = (const float*)d_in[20];
  const float* g2   = (const float*)d_in[21];
  const float* be2  = (const float*)d_in[22];
  const float* temp = (const float*)d_in[23];
  const float* alph = (const float*)d_in[24];

  float* outp   = (float*)d_out;
  float* attn_o = outp + (size_t)BSZ*CHN*NPT*LW;          // 614400
  float* p2_o   = attn_o + (size_t)BSZ*NH*LW*NPT*NPT;     // +30720000

  const size_t SLICE = (size_t)BSZ*LW*NH*NPT*HDM;         // 2457600
  float* w   = (float*)d_ws;
  float* q1n = w;             w += SLICE;
  float* q2n = w;             w += SLICE;
  float* k1n = w;             w += SLICE;
  float* k2n = w;             w += SLICE;
  float* vv  = w;             w += SLICE;
  float* oa  = w;             w += (size_t)NTOK*DM;

  stage_a<<<NTOK/TA, 128, 0, stream>>>(x, xa1, xa2, WQ1, bQ1, WQ2, bQ2,
                                       WK1, bK1, WK2, bK2, WV, bV,
                                       q1n, q2n, k1n, k2n, vv);
  stage_b<<<BSZ*NH*LW*4, 256, 0, stream>>>(q1n, q2n, k1n, k2n, vv,
                                           temp, alph, attn_o, p2_o, oa);
  stage_c<<<NTOK/TC, 256, 0, stream>>>(oa, x, Wo, bo, Wf1, bf1, Wf2, bf2,
                                       g1, be1, g2, be2, outp);
}

// Round 5
// 1338.269 us; speedup vs baseline: 1.3356x; 1.3113x over previous
//
#include <hip/hip_runtime.h>
#include <math.h>

#define BSZ 2
#define CHN 64
#define NPT 400
#define LW  12
#define DM  128
#define NH  8
#define HDM 16
#define FFD 1024
#define NTOK (BSZ*LW*NPT)   // 9600

// ------------------------------------------------------------------
// Stage A: QKV projections + per-head l2norm.
// out layout: [b][l][h][n][d]  (contiguous 400x16 slice per (b,l,h))
// ------------------------------------------------------------------
#define TA 16
__global__ __launch_bounds__(128) void stage_a(
    const float* __restrict__ x, const float* __restrict__ xa1, const float* __restrict__ xa2,
    const float* __restrict__ WQ1, const float* __restrict__ bQ1,
    const float* __restrict__ WQ2, const float* __restrict__ bQ2,
    const float* __restrict__ WK1, const float* __restrict__ bK1,
    const float* __restrict__ WK2, const float* __restrict__ bK2,
    const float* __restrict__ WV,  const float* __restrict__ bV,
    float* __restrict__ q1n, float* __restrict__ q2n,
    float* __restrict__ k1n, float* __restrict__ k2n, float* __restrict__ vv)
{
  __shared__ float xv[TA][CHN], a1v[TA][CHN], a2v[TA][CHN];
  const int tid = threadIdx.x;
  const int t0 = blockIdx.x * TA;
  for (int i = tid; i < TA*CHN; i += 128) {
    int tt = i & (TA-1), c = i >> 4;
    int token = t0 + tt;
    int n = token % NPT; int bl = token / NPT; int l = bl % LW; int b = bl / LW;
    int gidx = ((b*CHN + c)*NPT + n)*LW + l;
    xv[tt][c] = x[gidx]; a1v[tt][c] = xa1[gidx]; a2v[tt][c] = xa2[gidx];
  }
  __syncthreads();
  const int d = tid;  // 0..127
  float aq1[TA], aq2[TA], ak1[TA], ak2[TA], av[TA];
  float b1 = bQ1[d], b2 = bQ2[d], b3 = bK1[d], b4 = bK2[d], b5 = bV[d];
  #pragma unroll
  for (int t = 0; t < TA; ++t) { aq1[t]=b1; aq2[t]=b2; ak1[t]=b3; ak2[t]=b4; av[t]=b5; }
  for (int c = 0; c < CHN; ++c) {
    float w1 = WQ1[c*DM + d], w2 = WQ2[c*DM + d], w3 = WK1[c*DM + d],
          w4 = WK2[c*DM + d], w5 = WV[c*DM + d];
    #pragma unroll
    for (int t = 0; t < TA; ++t) {
      float xc = xv[t][c], x1 = a1v[t][c], x2 = a2v[t][c];
      aq1[t] += x1*w1; aq2[t] += x2*w2; ak1[t] += xc*w3; ak2[t] += xc*w4; av[t] += xc*w5;
    }
  }
  const int h = d >> 4, dd = d & 15;
  #pragma unroll
  for (int t = 0; t < TA; ++t) {
    float s1 = aq1[t]*aq1[t], s2 = aq2[t]*aq2[t], s3 = ak1[t]*ak1[t], s4 = ak2[t]*ak2[t];
    #pragma unroll
    for (int m = 1; m < 16; m <<= 1) {
      s1 += __shfl_xor(s1, m); s2 += __shfl_xor(s2, m);
      s3 += __shfl_xor(s3, m); s4 += __shfl_xor(s4, m);
    }
    float i1 = 1.f/fmaxf(sqrtf(s1),1e-12f), i2 = 1.f/fmaxf(sqrtf(s2),1e-12f),
          i3 = 1.f/fmaxf(sqrtf(s3),1e-12f), i4 = 1.f/fmaxf(sqrtf(s4),1e-12f);
    int token = t0 + t;
    int n = token % NPT; int bl = token / NPT; int l = bl % LW; int b = bl / LW;
    int base = (((b*LW + l)*NH + h)*NPT + n)*HDM + dd;
    q1n[base] = aq1[t]*i1; q2n[base] = aq2[t]*i2;
    k1n[base] = ak1[t]*i3; k2n[base] = ak2[t]*i4; vv[base] = av[t];
  }
}

// ------------------------------------------------------------------
// Stage B: fused dual-cosine attention + exact top-k dual softmax + PV
// Grid: (b,h,l, split s of 100 rows) = 768 WGs x 256 threads
// v5: V-from-global REFUTED by counters (FETCH 2.0GB == zero-reuse
//     sector model; nt stores changed nothing). V back in LDS (77KB,
//     2 WG/CU). Keep: merged+guarded radix, PV d-halves (buf[32],
//     VGPR~84), nt stores for attn/p2.
//     Watch: WRITE_SIZE 2.28GB vs 276MB payload (9x, unexplained).
// ------------------------------------------------------------------
__device__ __forceinline__ unsigned okey(float xf) {
  unsigned u = __float_as_uint(xf);
  return (u & 0x80000000u) ? ~u : (u | 0x80000000u);
}

__global__ __launch_bounds__(256, 2) void stage_b(
    const float* __restrict__ q1n, const float* __restrict__ q2n,
    const float* __restrict__ k1n, const float* __restrict__ k2n,
    const float* __restrict__ vv,
    const float* __restrict__ temperature, const float* __restrict__ alphas,
    float* __restrict__ attn_o, float* __restrict__ p2_o, float* __restrict__ oa)
{
  // d-chunk planes, stride 401 float4 per plane: stride-1 b128 reads, conflict-free
  __shared__ float4 k1s[4*401], k2s[4*401], vs[4*401];
  int wg = blockIdx.x;
  const int s = wg & 3; wg >>= 2;
  const int l = wg % LW; wg /= LW;
  const int h = wg & 7; const int b = wg >> 3;
  const int tid = threadIdx.x, lane = tid & 63, wave = tid >> 6;

  const int slice = (b*LW + l)*NH + h;          // internal q/k/v layout [b][l][h]
  const int oslice = (b*NH + h)*LW + l;         // OUTPUT layout [b][h][l] (reshape bs*H, L, N, N)
  const float4* k1g = (const float4*)(k1n + slice*NPT*HDM);
  const float4* k2g = (const float4*)(k2n + slice*NPT*HDM);
  const float4* vg  = (const float4*)(vv  + slice*NPT*HDM);
  for (int i = tid; i < NPT*4; i += 256) {
    int m = i >> 2, w4 = i & 3;
    k1s[w4*401 + m] = k1g[i];
    k2s[w4*401 + m] = k2g[i];
    vs [w4*401 + m] = vg[i];
  }
  __syncthreads();

  const float temp = temperature[h];
  float a0 = alphas[0], a1 = alphas[1];
  float amx = fmaxf(a0, a1);
  float e0 = __expf(a0 - amx), e1 = __expf(a1 - amx);
  float al0 = e0/(e0+e1), al1 = e1/(e0+e1);

  const float* q1base = q1n + slice*NPT*HDM;
  const float* q2base = q2n + slice*NPT*HDM;
  float* attn_base = attn_o + (size_t)oslice*NPT*NPT;
  float* p2_base   = p2_o   + (size_t)oslice*NPT*NPT;
  const int tokbase = (b*LW + l)*NPT;

  for (int bi = wave; bi < 25; bi += 4) {
    const int nb = s*100 + bi*4;    // rows nb..nb+3
    float sc[4][7];
    #pragma unroll
    for (int r = 0; r < 4; ++r)
      #pragma unroll
      for (int j = 0; j < 7; ++j) sc[r][j] = 0.f;

    // ---- scores: Q1.K1 + Q2.K2 over d (16+16), 4 rows x 7 m's/lane ----
    // Q addresses are wave-uniform -> compiler scalarizes to SGPRs.
    #pragma unroll
    for (int ch = 0; ch < 4; ++ch) {
      float4 q1c[4], q2c[4];
      #pragma unroll
      for (int r = 0; r < 4; ++r) {
        q1c[r] = *(const float4*)(q1base + (nb+r)*HDM + ch*4);
        q2c[r] = *(const float4*)(q2base + (nb+r)*HDM + ch*4);
      }
      #pragma unroll
      for (int j = 0; j < 7; ++j) {
        int m = lane + 64*j;
        if (j < 6 || lane < 16) {
          float4 kc1 = k1s[ch*401 + m];
          float4 kc2 = k2s[ch*401 + m];
          #pragma unroll
          for (int r = 0; r < 4; ++r) {
            sc[r][j] += q1c[r].x*kc1.x + q1c[r].y*kc1.y + q1c[r].z*kc1.z + q1c[r].w*kc1.w
                      + q2c[r].x*kc2.x + q2c[r].y*kc2.y + q2c[r].z*kc2.z + q2c[r].w*kc2.w;
          }
        }
      }
    }
    // ---- temperature + attn output (non-temporal: write-once stream) ----
    #pragma unroll
    for (int r = 0; r < 4; ++r) {
      #pragma unroll
      for (int j = 0; j < 7; ++j) {
        sc[r][j] *= temp;
        int m = lane + 64*j;
        if (j < 6 || lane < 16)
          __builtin_nontemporal_store(sc[r][j], &attn_base[(nb + r)*NPT + m]);
      }
    }
    // ---- per-row: exact top-k select + dual softmax; overwrite sc with w ----
    #pragma unroll
    for (int r = 0; r < 4; ++r) {
      unsigned key[7];
      #pragma unroll
      for (int j = 0; j < 7; ++j) {
        bool valid = (j < 6) || (lane < 16);
        key[j] = valid ? okey(sc[r][j]) : 0u;
      }
      float am = -3.4e38f;
      #pragma unroll
      for (int j = 0; j < 7; ++j) if ((j < 6) || (lane < 16)) am = fmaxf(am, sc[r][j]);
      #pragma unroll
      for (int m2 = 1; m2 < 64; m2 <<= 1) am = fmaxf(am, __shfl_xor(am, m2));

      // merged dual radix descent: v1 (k=200) and v2 (k=100) in one bit loop.
      // d1/d2 are wave-uniform -> guards are cheap s_cbranch; finished
      // descent stops issuing ballots.
      unsigned v1 = 0u, v2 = 0u;
      bool d1 = false, d2 = false;
      #pragma clang loop unroll(disable)
      for (int bit = 31; bit >= 0; --bit) {
        if (!d1) {
          unsigned T1 = v1 | (1u << bit);
          int c1 = 0;
          #pragma unroll
          for (int j = 0; j < 7; ++j) c1 += __popcll(__ballot(key[j] >= T1));
          if (c1 >= 200) { v1 = T1; if (c1 == 200) d1 = true; }
        }
        if (!d2) {
          unsigned T2 = v2 | (1u << bit);
          int c2 = 0;
          #pragma unroll
          for (int j = 0; j < 7; ++j) c2 += __popcll(__ballot(key[j] >= T2));
          if (c2 >= 100) { v2 = T2; if (c2 == 100) d2 = true; }
        }
        if (d1 && d2) break;
      }

      float e[7]; float s1 = 0.f, s2 = 0.f;
      #pragma unroll
      for (int j = 0; j < 7; ++j) {
        e[j] = ((j < 6) || (lane < 16)) ? __expf(sc[r][j] - am) : 0.f;
        s1 += (key[j] >= v1) ? e[j] : 0.f;
        s2 += (key[j] >= v2) ? e[j] : 0.f;
      }
      #pragma unroll
      for (int m2 = 1; m2 < 64; m2 <<= 1) { s1 += __shfl_xor(s1, m2); s2 += __shfl_xor(s2, m2); }
      float rz1 = 1.f / s1, rz2 = 1.f / s2;
      float c1 = al0 * rz1, c2 = al1 * rz2;
      #pragma unroll
      for (int j = 0; j < 7; ++j) {
        int m = lane + 64*j;
        float p2v = (key[j] >= v2) ? e[j]*rz2 : 0.f;
        if ((j < 6) || (lane < 16))
          __builtin_nontemporal_store(p2v, &p2_base[(nb + r)*NPT + m]);
        sc[r][j] = e[j] * (((key[j] >= v1) ? c1 : 0.f) + ((key[j] >= v2) ? c2 : 0.f));
      }
    }
    // ---- PV in two d-halves from LDS planes: half0 -> d 0..7 (planes 0,1),
    //      half1 -> d 8..15 (planes 2,3). buf[32] keeps VGPR low. ----
    #pragma unroll
    for (int half = 0; half < 2; ++half) {
      float buf[32];
      #pragma unroll
      for (int i = 0; i < 32; ++i) buf[i] = 0.f;
      #pragma unroll
      for (int j = 0; j < 7; ++j) {
        int m = lane + 64*j;
        if (j < 6 || lane < 16) {
          float4 w0 = vs[(half*2+0)*401 + m];
          float4 w1 = vs[(half*2+1)*401 + m];
          #pragma unroll
          for (int r = 0; r < 4; ++r) {
            float wr = sc[r][j];
            buf[r*8+0] += wr*w0.x; buf[r*8+1] += wr*w0.y;
            buf[r*8+2] += wr*w0.z; buf[r*8+3] += wr*w0.w;
            buf[r*8+4] += wr*w1.x; buf[r*8+5] += wr*w1.y;
            buf[r*8+6] += wr*w1.z; buf[r*8+7] += wr*w1.w;
          }
        }
      }
      // reduce-scatter 32 elems over lanes (bits 0..4), then fold lane^32.
      #pragma unroll
      for (int st = 0; st < 5; ++st) {
        int bsel = (lane >> st) & 1;
        #pragma unroll
        for (int u = 0; u < (32 >> (st+1)); ++u) {
          float lo = buf[2*u], hi = buf[2*u+1];
          float keep = bsel ? hi : lo;
          float send = bsel ? lo : hi;
          float recv = __shfl_xor(send, 1 << st);
          buf[u] = keep + recv;
        }
      }
      float res = buf[0] + __shfl_xor(buf[0], 32);
      if (lane < 32) {
        int rr = lane >> 3, dlo = lane & 7;
        oa[(tokbase + nb + rr)*DM + h*HDM + half*8 + dlo] = res;
      }
    }
  }
}

// ------------------------------------------------------------------
// Stage C: Wo + residual + LN1 + FF + LN2 + transpose-out
// Grid: 300 WGs x 256 threads, 32 tokens/WG
// ------------------------------------------------------------------
#define TC 32
__global__ __launch_bounds__(256, 2) void stage_c(
    const float* __restrict__ oa, const float* __restrict__ x,
    const float* __restrict__ Wo, const float* __restrict__ bo,
    const float* __restrict__ Wf1, const float* __restrict__ bf1,
    const float* __restrict__ Wf2, const float* __restrict__ bf2,
    const float* __restrict__ g1, const float* __restrict__ be1,
    const float* __restrict__ g2, const float* __restrict__ be2,
    float* __restrict__ outp)
{
  __shared__ float4 oa_lds[TC*32];   // 16 KB
  __shared__ float4 y1_lds[TC*16];   // 8 KB
  __shared__ float4 act_lds[TC*64];  // 32 KB
  const int tid = threadIdx.x;
  const int t0 = blockIdx.x * TC;
  const float4* oag = (const float4*)(oa + t0*DM);
  for (int i = tid; i < TC*32; i += 256) oa_lds[i] = oag[i];
  __syncthreads();

  const int c = tid & 63, g = tid >> 6;   // tokens tt = g + 4k, k=0..7
  float bo_c = bo[c], g1c = g1[c], be1c = be1[c], g2c = g2[c], be2c = be2[c], bf2c = bf2[c];

  // P1: o1 = oa @ Wo + bo
  float o1[8];
  #pragma unroll
  for (int k = 0; k < 8; ++k) o1[k] = bo_c;
  for (int d4 = 0; d4 < 32; ++d4) {
    float w0 = Wo[(4*d4+0)*CHN + c];
    float w1 = Wo[(4*d4+1)*CHN + c];
    float w2 = Wo[(4*d4+2)*CHN + c];
    float w3 = Wo[(4*d4+3)*CHN + c];
    #pragma unroll
    for (int k = 0; k < 8; ++k) {
      float4 u = oa_lds[(g + 4*k)*32 + d4];
      o1[k] += u.x*w0 + u.y*w1 + u.z*w2 + u.w*w3;
    }
  }
  // residual + LN1
  float y1r[8];
  #pragma unroll
  for (int k = 0; k < 8; ++k) {
    int token = t0 + g + 4*k;
    int n = token % NPT; int bl = token / NPT; int l = bl % LW; int b = bl / LW;
    float val = o1[k] + x[((b*CHN + c)*NPT + n)*LW + l];
    float sm = val, sq = val*val;
    #pragma unroll
    for (int m2 = 1; m2 < 64; m2 <<= 1) { sm += __shfl_xor(sm, m2); sq += __shfl_xor(sq, m2); }
    float mean = sm * (1.f/64.f);
    float var = sq * (1.f/64.f) - mean*mean;
    float y = (val - mean) * rsqrtf(var + 1e-5f) * g1c + be1c;
    y1r[k] = y;
    ((float*)y1_lds)[(g + 4*k)*CHN + c] = y;
  }
  __syncthreads();

  float o2a[8];
  #pragma unroll
  for (int k = 0; k < 8; ++k) o2a[k] = 0.f;

  for (int fb = 0; fb < 4; ++fb) {
    // 2a: act = relu(y1 @ Wf1 + bf1) for 256 f's
    {
      const int ft = tid & 63, ga = tid >> 6;
      const int f = fb*256 + ft*4;
      float4 facc[8];
      float4 bb = *(const float4*)(bf1 + f);
      #pragma unroll
      for (int k = 0; k < 8; ++k) facc[k] = bb;
      for (int c4 = 0; c4 < 16; ++c4) {
        float4 w0 = *(const float4*)(Wf1 + (4*c4+0)*FFD + f);
        float4 w1 = *(const float4*)(Wf1 + (4*c4+1)*FFD + f);
        float4 w2 = *(const float4*)(Wf1 + (4*c4+2)*FFD + f);
        float4 w3 = *(const float4*)(Wf1 + (4*c4+3)*FFD + f);
        #pragma unroll
        for (int k = 0; k < 8; ++k) {
          float4 y4 = y1_lds[(ga + 4*k)*16 + c4];
          facc[k].x += y4.x*w0.x + y4.y*w1.x + y4.z*w2.x + y4.w*w3.x;
          facc[k].y += y4.x*w0.y + y4.y*w1.y + y4.z*w2.y + y4.w*w3.y;
          facc[k].z += y4.x*w0.z + y4.y*w1.z + y4.z*w2.z + y4.w*w3.z;
          facc[k].w += y4.x*w0.w + y4.y*w1.w + y4.z*w2.w + y4.w*w3.w;
        }
      }
      #pragma unroll
      for (int k = 0; k < 8; ++k) {
        float4 rv;
        rv.x = fmaxf(facc[k].x, 0.f); rv.y = fmaxf(facc[k].y, 0.f);
        rv.z = fmaxf(facc[k].z, 0.f); rv.w = fmaxf(facc[k].w, 0.f);
        act_lds[(ga + 4*k)*64 + ft] = rv;
      }
    }
    __syncthreads();
    // 2b: o2 += act @ Wf2
    for (int f4 = 0; f4 < 64; ++f4) {
      int f = fb*256 + f4*4;
      float w0 = Wf2[(f+0)*CHN + c];
      float w1 = Wf2[(f+1)*CHN + c];
      float w2 = Wf2[(f+2)*CHN + c];
      float w3 = Wf2[(f+3)*CHN + c];
      #pragma unroll
      for (int k = 0; k < 8; ++k) {
        float4 a4 = act_lds[(g + 4*k)*64 + f4];
        o2a[k] += a4.x*w0 + a4.y*w1 + a4.z*w2 + a4.w*w3;
      }
    }
    __syncthreads();
  }
  // P3: + bf2, residual y1, LN2, transposed store
  #pragma unroll
  for (int k = 0; k < 8; ++k) {
    int token = t0 + g + 4*k;
    int n = token % NPT; int bl = token / NPT; int l = bl % LW; int b = bl / LW;
    float val = y1r[k] + o2a[k] + bf2c;
    float sm = val, sq = val*val;
    #pragma unroll
    for (int m2 = 1; m2 < 64; m2 <<= 1) { sm += __shfl_xor(sm, m2); sq += __shfl_xor(sq, m2); }
    float mean = sm * (1.f/64.f);
    float var = sq * (1.f/64.f) - mean*mean;
    float y = (val - mean) * rsqrtf(var + 1e-5f) * g2c + be2c;
    outp[((b*CHN + c)*NPT + n)*LW + l] = y;
  }
}

// ------------------------------------------------------------------
extern "C" void kernel_launch(void* const* d_in, const int* in_sizes, int n_in,
                              void* d_out, int out_size, void* d_ws, size_t ws_size,
                              hipStream_t stream) {
  const float* x    = (const float*)d_in[0];
  const float* xa1  = (const float*)d_in[1];
  const float* xa2  = (const float*)d_in[2];
  const float* WQ1  = (const float*)d_in[3];
  const float* bQ1  = (const float*)d_in[4];
  const float* WQ2  = (const float*)d_in[5];
  const float* bQ2  = (const float*)d_in[6];
  const float* WK1  = (const float*)d_in[7];
  const float* bK1  = (const float*)d_in[8];
  const float* WK2  = (const float*)d_in[9];
  const float* bK2  = (const float*)d_in[10];
  const float* WV   = (const float*)d_in[11];
  const float* bV   = (const float*)d_in[12];
  const float* Wo   = (const float*)d_in[13];
  const float* bo   = (const float*)d_in[14];
  const float* Wf1  = (const float*)d_in[15];
  const float* bf1  = (const float*)d_in[16];
  const float* Wf2  = (const float*)d_in[17];
  const float* bf2  = (const float*)d_in[18];
  const float* g1   = (const float*)d_in[19];
  const float* be1  = (const float*)d_in[20];
  const float* g2   = (const float*)d_in[21];
  const float* be2  = (const float*)d_in[22];
  const float* temp = (const float*)d_in[23];
  const float* alph = (const float*)d_in[24];

  float* outp   = (float*)d_out;
  float* attn_o = outp + (size_t)BSZ*CHN*NPT*LW;          // 614400
  float* p2_o   = attn_o + (size_t)BSZ*NH*LW*NPT*NPT;     // +30720000

  const size_t SLICE = (size_t)BSZ*LW*NH*NPT*HDM;         // 2457600
  float* w   = (float*)d_ws;
  float* q1n = w;             w += SLICE;
  float* q2n = w;             w += SLICE;
  float* k1n = w;             w += SLICE;
  float* k2n = w;             w += SLICE;
  float* vv  = w;             w += SLICE;
  float* oa  = w;             w += (size_t)NTOK*DM;

  stage_a<<<NTOK/TA, 128, 0, stream>>>(x, xa1, xa2, WQ1, bQ1, WQ2, bQ2,
                                       WK1, bK1, WK2, bK2, WV, bV,
                                       q1n, q2n, k1n, k2n, vv);
  stage_b<<<BSZ*NH*LW*4, 256, 0, stream>>>(q1n, q2n, k1n, k2n, vv,
                                           temp, alph, attn_o, p2_o, oa);
  stage_c<<<NTOK/TC, 256, 0, stream>>>(oa, x, Wo, bo, Wf1, bf1, Wf2, bf2,
                                       g1, be1, g2, be2, outp);
}

// Round 6
// 1210.562 us; speedup vs baseline: 1.4765x; 1.1055x over previous
//
#include <hip/hip_runtime.h>
#include <math.h>

#define BSZ 2
#define CHN 64
#define NPT 400
#define LW  12
#define DM  128
#define NH  8
#define HDM 16
#define FFD 1024
#define NTOK (BSZ*LW*NPT)   // 9600
#define SPLIT 8             // s-chunks per (b,h,l): 1536 WGs = 3 exact rounds of 512

// ------------------------------------------------------------------
// Stage A: QKV projections + per-head l2norm.
// out layout: [b][l][h][n][d]  (contiguous 400x16 slice per (b,l,h))
// ------------------------------------------------------------------
#define TA 16
__global__ __launch_bounds__(128) void stage_a(
    const float* __restrict__ x, const float* __restrict__ xa1, const float* __restrict__ xa2,
    const float* __restrict__ WQ1, const float* __restrict__ bQ1,
    const float* __restrict__ WQ2, const float* __restrict__ bQ2,
    const float* __restrict__ WK1, const float* __restrict__ bK1,
    const float* __restrict__ WK2, const float* __restrict__ bK2,
    const float* __restrict__ WV,  const float* __restrict__ bV,
    float* __restrict__ q1n, float* __restrict__ q2n,
    float* __restrict__ k1n, float* __restrict__ k2n, float* __restrict__ vv)
{
  __shared__ float xv[TA][CHN], a1v[TA][CHN], a2v[TA][CHN];
  const int tid = threadIdx.x;
  const int t0 = blockIdx.x * TA;
  for (int i = tid; i < TA*CHN; i += 128) {
    int tt = i & (TA-1), c = i >> 4;
    int token = t0 + tt;
    int n = token % NPT; int bl = token / NPT; int l = bl % LW; int b = bl / LW;
    int gidx = ((b*CHN + c)*NPT + n)*LW + l;
    xv[tt][c] = x[gidx]; a1v[tt][c] = xa1[gidx]; a2v[tt][c] = xa2[gidx];
  }
  __syncthreads();
  const int d = tid;  // 0..127
  float aq1[TA], aq2[TA], ak1[TA], ak2[TA], av[TA];
  float b1 = bQ1[d], b2 = bQ2[d], b3 = bK1[d], b4 = bK2[d], b5 = bV[d];
  #pragma unroll
  for (int t = 0; t < TA; ++t) { aq1[t]=b1; aq2[t]=b2; ak1[t]=b3; ak2[t]=b4; av[t]=b5; }
  for (int c = 0; c < CHN; ++c) {
    float w1 = WQ1[c*DM + d], w2 = WQ2[c*DM + d], w3 = WK1[c*DM + d],
          w4 = WK2[c*DM + d], w5 = WV[c*DM + d];
    #pragma unroll
    for (int t = 0; t < TA; ++t) {
      float xc = xv[t][c], x1 = a1v[t][c], x2 = a2v[t][c];
      aq1[t] += x1*w1; aq2[t] += x2*w2; ak1[t] += xc*w3; ak2[t] += xc*w4; av[t] += xc*w5;
    }
  }
  const int h = d >> 4, dd = d & 15;
  #pragma unroll
  for (int t = 0; t < TA; ++t) {
    float s1 = aq1[t]*aq1[t], s2 = aq2[t]*aq2[t], s3 = ak1[t]*ak1[t], s4 = ak2[t]*ak2[t];
    #pragma unroll
    for (int m = 1; m < 16; m <<= 1) {
      s1 += __shfl_xor(s1, m); s2 += __shfl_xor(s2, m);
      s3 += __shfl_xor(s3, m); s4 += __shfl_xor(s4, m);
    }
    float i1 = 1.f/fmaxf(sqrtf(s1),1e-12f), i2 = 1.f/fmaxf(sqrtf(s2),1e-12f),
          i3 = 1.f/fmaxf(sqrtf(s3),1e-12f), i4 = 1.f/fmaxf(sqrtf(s4),1e-12f);
    int token = t0 + t;
    int n = token % NPT; int bl = token / NPT; int l = bl % LW; int b = bl / LW;
    int base = (((b*LW + l)*NH + h)*NPT + n)*HDM + dd;
    q1n[base] = aq1[t]*i1; q2n[base] = aq2[t]*i2;
    k1n[base] = ak1[t]*i3; k2n[base] = ak2[t]*i4; vv[base] = av[t];
  }
}

// ------------------------------------------------------------------
// Stage B: fused dual-cosine attention + exact top-k dual softmax + PV
// v6: counters showed v5 NOT BW-bound (2.1GB @ 2.3TB/s = 37% achievable,
//     VALUBusy 11%, occ 16.6%) -> latency-bound + bad round packing
//     (768 WGs at 2 WG/CU = 512-cap -> half-machine tail).
//     Fix 1: SPLIT=8 -> 1536 WGs = 3 exact full rounds.
//     Fix 2: interleave all 8 radix descents (4 rows x 2 k) in ONE bit
//     loop -> 8-way ILP on the serial ballot chain; interleaved am
//     reduction. LDS/staging layout unchanged from v5.
// ------------------------------------------------------------------
__device__ __forceinline__ unsigned okey(float xf) {
  unsigned u = __float_as_uint(xf);
  return (u & 0x80000000u) ? ~u : (u | 0x80000000u);
}

__global__ __launch_bounds__(256, 2) void stage_b(
    const float* __restrict__ q1n, const float* __restrict__ q2n,
    const float* __restrict__ k1n, const float* __restrict__ k2n,
    const float* __restrict__ vv,
    const float* __restrict__ temperature, const float* __restrict__ alphas,
    float* __restrict__ attn_o, float* __restrict__ p2_o, float* __restrict__ oa)
{
  // d-chunk planes, stride 401 float4 per plane: stride-1 b128 reads, conflict-free
  __shared__ float4 k1s[4*401], k2s[4*401], vs[4*401];
  int wg = blockIdx.x;
  const int s = wg & (SPLIT-1); wg /= SPLIT;
  const int l = wg % LW; wg /= LW;
  const int h = wg & 7; const int b = wg >> 3;
  const int tid = threadIdx.x, lane = tid & 63, wave = tid >> 6;

  // block range for this s-chunk: 100 4-row blocks split 13/13/13/13/12/12/12/12
  const int g0  = s*12 + (s < 4 ? s : 4);
  const int cnt = (s < 4) ? 13 : 12;

  const int slice = (b*LW + l)*NH + h;          // internal q/k/v layout [b][l][h]
  const int oslice = (b*NH + h)*LW + l;         // OUTPUT layout [b][h][l] (reshape bs*H, L, N, N)
  const float4* k1g = (const float4*)(k1n + slice*NPT*HDM);
  const float4* k2g = (const float4*)(k2n + slice*NPT*HDM);
  const float4* vg  = (const float4*)(vv  + slice*NPT*HDM);
  for (int i = tid; i < NPT*4; i += 256) {
    int m = i >> 2, w4 = i & 3;
    k1s[w4*401 + m] = k1g[i];
    k2s[w4*401 + m] = k2g[i];
    vs [w4*401 + m] = vg[i];
  }
  __syncthreads();

  const float temp = temperature[h];
  float a0 = alphas[0], a1 = alphas[1];
  float amx = fmaxf(a0, a1);
  float e0 = __expf(a0 - amx), e1 = __expf(a1 - amx);
  float al0 = e0/(e0+e1), al1 = e1/(e0+e1);

  const float* q1base = q1n + slice*NPT*HDM;
  const float* q2base = q2n + slice*NPT*HDM;
  float* attn_base = attn_o + (size_t)oslice*NPT*NPT;
  float* p2_base   = p2_o   + (size_t)oslice*NPT*NPT;
  const int tokbase = (b*LW + l)*NPT;

  for (int bi = wave; bi < cnt; bi += 4) {
    const int nb = (g0 + bi)*4;     // rows nb..nb+3
    float sc[4][7];
    #pragma unroll
    for (int r = 0; r < 4; ++r)
      #pragma unroll
      for (int j = 0; j < 7; ++j) sc[r][j] = 0.f;

    // ---- scores: Q1.K1 + Q2.K2 over d (16+16), 4 rows x 7 m's/lane ----
    #pragma unroll
    for (int ch = 0; ch < 4; ++ch) {
      float4 q1c[4], q2c[4];
      #pragma unroll
      for (int r = 0; r < 4; ++r) {
        q1c[r] = *(const float4*)(q1base + (nb+r)*HDM + ch*4);
        q2c[r] = *(const float4*)(q2base + (nb+r)*HDM + ch*4);
      }
      #pragma unroll
      for (int j = 0; j < 7; ++j) {
        int m = lane + 64*j;
        if (j < 6 || lane < 16) {
          float4 kc1 = k1s[ch*401 + m];
          float4 kc2 = k2s[ch*401 + m];
          #pragma unroll
          for (int r = 0; r < 4; ++r) {
            sc[r][j] += q1c[r].x*kc1.x + q1c[r].y*kc1.y + q1c[r].z*kc1.z + q1c[r].w*kc1.w
                      + q2c[r].x*kc2.x + q2c[r].y*kc2.y + q2c[r].z*kc2.z + q2c[r].w*kc2.w;
          }
        }
      }
    }
    // ---- temperature + attn output (non-temporal: write-once stream) ----
    #pragma unroll
    for (int r = 0; r < 4; ++r) {
      #pragma unroll
      for (int j = 0; j < 7; ++j) {
        sc[r][j] *= temp;
        int m = lane + 64*j;
        if (j < 6 || lane < 16)
          __builtin_nontemporal_store(sc[r][j], &attn_base[(nb + r)*NPT + m]);
      }
    }
    // ---- keys for all 4 rows (invalid lanes -> 0 so they never pass) ----
    unsigned key[4][7];
    #pragma unroll
    for (int r = 0; r < 4; ++r)
      #pragma unroll
      for (int j = 0; j < 7; ++j) {
        bool valid = (j < 6) || (lane < 16);
        key[r][j] = valid ? okey(sc[r][j]) : 0u;
      }
    // ---- row maxes, 4 rows interleaved through one shuffle ladder ----
    float am[4];
    #pragma unroll
    for (int r = 0; r < 4; ++r) {
      float a = -3.4e38f;
      #pragma unroll
      for (int j = 0; j < 7; ++j) if ((j < 6) || (lane < 16)) a = fmaxf(a, sc[r][j]);
      am[r] = a;
    }
    #pragma unroll
    for (int m2 = 1; m2 < 64; m2 <<= 1) {
      #pragma unroll
      for (int r = 0; r < 4; ++r) am[r] = fmaxf(am[r], __shfl_xor(am[r], m2));
    }
    // ---- 8 radix descents (4 rows x {k=200, k=100}) in ONE bit loop ----
    // done bits: r -> v1[r] finished, 4+r -> v2[r] finished (wave-uniform)
    unsigned v1[4] = {0u,0u,0u,0u}, v2[4] = {0u,0u,0u,0u};
    unsigned done = 0u;
    #pragma clang loop unroll(disable)
    for (int bit = 31; bit >= 0; --bit) {
      #pragma unroll
      for (int r = 0; r < 4; ++r) {
        if (!(done & (1u << r))) {
          unsigned T = v1[r] | (1u << bit);
          int c = 0;
          #pragma unroll
          for (int j = 0; j < 7; ++j) c += __popcll(__ballot(key[r][j] >= T));
          if (c >= 200) { v1[r] = T; if (c == 200) done |= (1u << r); }
        }
        if (!(done & (16u << r))) {
          unsigned T = v2[r] | (1u << bit);
          int c = 0;
          #pragma unroll
          for (int j = 0; j < 7; ++j) c += __popcll(__ballot(key[r][j] >= T));
          if (c >= 100) { v2[r] = T; if (c == 100) done |= (16u << r); }
        }
      }
      if (done == 0xFFu) break;
    }
    // ---- per-row dual softmax + p2 store; overwrite sc with PV weights ----
    #pragma unroll
    for (int r = 0; r < 4; ++r) {
      float e[7]; float s1 = 0.f, s2 = 0.f;
      #pragma unroll
      for (int j = 0; j < 7; ++j) {
        e[j] = ((j < 6) || (lane < 16)) ? __expf(sc[r][j] - am[r]) : 0.f;
        s1 += (key[r][j] >= v1[r]) ? e[j] : 0.f;
        s2 += (key[r][j] >= v2[r]) ? e[j] : 0.f;
      }
      #pragma unroll
      for (int m2 = 1; m2 < 64; m2 <<= 1) { s1 += __shfl_xor(s1, m2); s2 += __shfl_xor(s2, m2); }
      float rz1 = 1.f / s1, rz2 = 1.f / s2;
      float c1 = al0 * rz1, c2 = al1 * rz2;
      #pragma unroll
      for (int j = 0; j < 7; ++j) {
        int m = lane + 64*j;
        float p2v = (key[r][j] >= v2[r]) ? e[j]*rz2 : 0.f;
        if ((j < 6) || (lane < 16))
          __builtin_nontemporal_store(p2v, &p2_base[(nb + r)*NPT + m]);
        sc[r][j] = e[j] * (((key[r][j] >= v1[r]) ? c1 : 0.f) + ((key[r][j] >= v2[r]) ? c2 : 0.f));
      }
    }
    // ---- PV in two d-halves from LDS planes ----
    #pragma unroll
    for (int half = 0; half < 2; ++half) {
      float buf[32];
      #pragma unroll
      for (int i = 0; i < 32; ++i) buf[i] = 0.f;
      #pragma unroll
      for (int j = 0; j < 7; ++j) {
        int m = lane + 64*j;
        if (j < 6 || lane < 16) {
          float4 w0 = vs[(half*2+0)*401 + m];
          float4 w1 = vs[(half*2+1)*401 + m];
          #pragma unroll
          for (int r = 0; r < 4; ++r) {
            float wr = sc[r][j];
            buf[r*8+0] += wr*w0.x; buf[r*8+1] += wr*w0.y;
            buf[r*8+2] += wr*w0.z; buf[r*8+3] += wr*w0.w;
            buf[r*8+4] += wr*w1.x; buf[r*8+5] += wr*w1.y;
            buf[r*8+6] += wr*w1.z; buf[r*8+7] += wr*w1.w;
          }
        }
      }
      // reduce-scatter 32 elems over lanes (bits 0..4), then fold lane^32.
      #pragma unroll
      for (int st = 0; st < 5; ++st) {
        int bsel = (lane >> st) & 1;
        #pragma unroll
        for (int u = 0; u < (32 >> (st+1)); ++u) {
          float lo = buf[2*u], hi = buf[2*u+1];
          float keep = bsel ? hi : lo;
          float send = bsel ? lo : hi;
          float recv = __shfl_xor(send, 1 << st);
          buf[u] = keep + recv;
        }
      }
      float res = buf[0] + __shfl_xor(buf[0], 32);
      if (lane < 32) {
        int rr = lane >> 3, dlo = lane & 7;
        oa[(tokbase + nb + rr)*DM + h*HDM + half*8 + dlo] = res;
      }
    }
  }
}

// ------------------------------------------------------------------
// Stage C: Wo + residual + LN1 + FF + LN2 + transpose-out
// Grid: 300 WGs x 256 threads, 32 tokens/WG
// ------------------------------------------------------------------
#define TC 32
__global__ __launch_bounds__(256, 2) void stage_c(
    const float* __restrict__ oa, const float* __restrict__ x,
    const float* __restrict__ Wo, const float* __restrict__ bo,
    const float* __restrict__ Wf1, const float* __restrict__ bf1,
    const float* __restrict__ Wf2, const float* __restrict__ bf2,
    const float* __restrict__ g1, const float* __restrict__ be1,
    const float* __restrict__ g2, const float* __restrict__ be2,
    float* __restrict__ outp)
{
  __shared__ float4 oa_lds[TC*32];   // 16 KB
  __shared__ float4 y1_lds[TC*16];   // 8 KB
  __shared__ float4 act_lds[TC*64];  // 32 KB
  const int tid = threadIdx.x;
  const int t0 = blockIdx.x * TC;
  const float4* oag = (const float4*)(oa + t0*DM);
  for (int i = tid; i < TC*32; i += 256) oa_lds[i] = oag[i];
  __syncthreads();

  const int c = tid & 63, g = tid >> 6;   // tokens tt = g + 4k, k=0..7
  float bo_c = bo[c], g1c = g1[c], be1c = be1[c], g2c = g2[c], be2c = be2[c], bf2c = bf2[c];

  // P1: o1 = oa @ Wo + bo
  float o1[8];
  #pragma unroll
  for (int k = 0; k < 8; ++k) o1[k] = bo_c;
  for (int d4 = 0; d4 < 32; ++d4) {
    float w0 = Wo[(4*d4+0)*CHN + c];
    float w1 = Wo[(4*d4+1)*CHN + c];
    float w2 = Wo[(4*d4+2)*CHN + c];
    float w3 = Wo[(4*d4+3)*CHN + c];
    #pragma unroll
    for (int k = 0; k < 8; ++k) {
      float4 u = oa_lds[(g + 4*k)*32 + d4];
      o1[k] += u.x*w0 + u.y*w1 + u.z*w2 + u.w*w3;
    }
  }
  // residual + LN1
  float y1r[8];
  #pragma unroll
  for (int k = 0; k < 8; ++k) {
    int token = t0 + g + 4*k;
    int n = token % NPT; int bl = token / NPT; int l = bl % LW; int b = bl / LW;
    float val = o1[k] + x[((b*CHN + c)*NPT + n)*LW + l];
    float sm = val, sq = val*val;
    #pragma unroll
    for (int m2 = 1; m2 < 64; m2 <<= 1) { sm += __shfl_xor(sm, m2); sq += __shfl_xor(sq, m2); }
    float mean = sm * (1.f/64.f);
    float var = sq * (1.f/64.f) - mean*mean;
    float y = (val - mean) * rsqrtf(var + 1e-5f) * g1c + be1c;
    y1r[k] = y;
    ((float*)y1_lds)[(g + 4*k)*CHN + c] = y;
  }
  __syncthreads();

  float o2a[8];
  #pragma unroll
  for (int k = 0; k < 8; ++k) o2a[k] = 0.f;

  for (int fb = 0; fb < 4; ++fb) {
    // 2a: act = relu(y1 @ Wf1 + bf1) for 256 f's
    {
      const int ft = tid & 63, ga = tid >> 6;
      const int f = fb*256 + ft*4;
      float4 facc[8];
      float4 bb = *(const float4*)(bf1 + f);
      #pragma unroll
      for (int k = 0; k < 8; ++k) facc[k] = bb;
      for (int c4 = 0; c4 < 16; ++c4) {
        float4 w0 = *(const float4*)(Wf1 + (4*c4+0)*FFD + f);
        float4 w1 = *(const float4*)(Wf1 + (4*c4+1)*FFD + f);
        float4 w2 = *(const float4*)(Wf1 + (4*c4+2)*FFD + f);
        float4 w3 = *(const float4*)(Wf1 + (4*c4+3)*FFD + f);
        #pragma unroll
        for (int k = 0; k < 8; ++k) {
          float4 y4 = y1_lds[(ga + 4*k)*16 + c4];
          facc[k].x += y4.x*w0.x + y4.y*w1.x + y4.z*w2.x + y4.w*w3.x;
          facc[k].y += y4.x*w0.y + y4.y*w1.y + y4.z*w2.y + y4.w*w3.y;
          facc[k].z += y4.x*w0.z + y4.y*w1.z + y4.z*w2.z + y4.w*w3.z;
          facc[k].w += y4.x*w0.w + y4.y*w1.w + y4.z*w2.w + y4.w*w3.w;
        }
      }
      #pragma unroll
      for (int k = 0; k < 8; ++k) {
        float4 rv;
        rv.x = fmaxf(facc[k].x, 0.f); rv.y = fmaxf(facc[k].y, 0.f);
        rv.z = fmaxf(facc[k].z, 0.f); rv.w = fmaxf(facc[k].w, 0.f);
        act_lds[(ga + 4*k)*64 + ft] = rv;
      }
    }
    __syncthreads();
    // 2b: o2 += act @ Wf2
    for (int f4 = 0; f4 < 64; ++f4) {
      int f = fb*256 + f4*4;
      float w0 = Wf2[(f+0)*CHN + c];
      float w1 = Wf2[(f+1)*CHN + c];
      float w2 = Wf2[(f+2)*CHN + c];
      float w3 = Wf2[(f+3)*CHN + c];
      #pragma unroll
      for (int k = 0; k < 8; ++k) {
        float4 a4 = act_lds[(g + 4*k)*64 + f4];
        o2a[k] += a4.x*w0 + a4.y*w1 + a4.z*w2 + a4.w*w3;
      }
    }
    __syncthreads();
  }
  // P3: + bf2, residual y1, LN2, transposed store
  #pragma unroll
  for (int k = 0; k < 8; ++k) {
    int token = t0 + g + 4*k;
    int n = token % NPT; int bl = token / NPT; int l = bl % LW; int b = bl / LW;
    float val = y1r[k] + o2a[k] + bf2c;
    float sm = val, sq = val*val;
    #pragma unroll
    for (int m2 = 1; m2 < 64; m2 <<= 1) { sm += __shfl_xor(sm, m2); sq += __shfl_xor(sq, m2); }
    float mean = sm * (1.f/64.f);
    float var = sq * (1.f/64.f) - mean*mean;
    float y = (val - mean) * rsqrtf(var + 1e-5f) * g2c + be2c;
    outp[((b*CHN + c)*NPT + n)*LW + l] = y;
  }
}

// ------------------------------------------------------------------
extern "C" void kernel_launch(void* const* d_in, const int* in_sizes, int n_in,
                              void* d_out, int out_size, void* d_ws, size_t ws_size,
                              hipStream_t stream) {
  const float* x    = (const float*)d_in[0];
  const float* xa1  = (const float*)d_in[1];
  const float* xa2  = (const float*)d_in[2];
  const float* WQ1  = (const float*)d_in[3];
  const float* bQ1  = (const float*)d_in[4];
  const float* WQ2  = (const float*)d_in[5];
  const float* bQ2  = (const float*)d_in[6];
  const float* WK1  = (const float*)d_in[7];
  const float* bK1  = (const float*)d_in[8];
  const float* WK2  = (const float*)d_in[9];
  const float* bK2  = (const float*)d_in[10];
  const float* WV   = (const float*)d_in[11];
  const float* bV   = (const float*)d_in[12];
  const float* Wo   = (const float*)d_in[13];
  const float* bo   = (const float*)d_in[14];
  const float* Wf1  = (const float*)d_in[15];
  const float* bf1  = (const float*)d_in[16];
  const float* Wf2  = (const float*)d_in[17];
  const float* bf2  = (const float*)d_in[18];
  const float* g1   = (const float*)d_in[19];
  const float* be1  = (const float*)d_in[20];
  const float* g2   = (const float*)d_in[21];
  const float* be2  = (const float*)d_in[22];
  const float* temp = (const float*)d_in[23];
  const float* alph = (const float*)d_in[24];

  float* outp   = (float*)d_out;
  float* attn_o = outp + (size_t)BSZ*CHN*NPT*LW;          // 614400
  float* p2_o   = attn_o + (size_t)BSZ*NH*LW*NPT*NPT;     // +30720000

  const size_t SLICE = (size_t)BSZ*LW*NH*NPT*HDM;         // 2457600
  float* w   = (float*)d_ws;
  float* q1n = w;             w += SLICE;
  float* q2n = w;             w += SLICE;
  float* k1n = w;             w += SLICE;
  float* k2n = w;             w += SLICE;
  float* vv  = w;             w += SLICE;
  float* oa  = w;             w += (size_t)NTOK*DM;

  stage_a<<<NTOK/TA, 128, 0, stream>>>(x, xa1, xa2, WQ1, bQ1, WQ2, bQ2,
                                       WK1, bK1, WK2, bK2, WV, bV,
                                       q1n, q2n, k1n, k2n, vv);
  stage_b<<<BSZ*NH*LW*SPLIT, 256, 0, stream>>>(q1n, q2n, k1n, k2n, vv,
                                               temp, alph, attn_o, p2_o, oa);
  stage_c<<<NTOK/TC, 256, 0, stream>>>(oa, x, Wo, bo, Wf1, bf1, Wf2, bf2,
                                       g1, be1, g2, be2, outp);
}